// Round 5
// baseline (86.743 us; speedup 1.0000x reference)
//
#include <hip/hip_runtime.h>

typedef __bf16 bf16x8 __attribute__((ext_vector_type(8)));
typedef float f32x4 __attribute__((ext_vector_type(4)));
typedef unsigned short u16x8 __attribute__((ext_vector_type(8)));

#define MFMA16(a, b, c) __builtin_amdgcn_mfma_f32_16x16x32_bf16((a), (b), (c), 0, 0, 0)

#define INVPI 0.31830988618379067f
#define TBL_N 4096
#define TBL_SCALE 409.6f          // TBL_N / gamma_range(10)
#define TBL_STEP (10.f / 4096.f)

__device__ __forceinline__ unsigned short f2bf(float f) {
    unsigned int u = __float_as_uint(f);
    u = u + 0x7FFFu + ((u >> 16) & 1u);   // round-to-nearest-even
    return (unsigned short)(u >> 16);
}

// f(y) = -y + sin^2(y+gamma) = 0.5 - 0.5*cos(2y+2gamma) - y
__device__ __forceinline__ float feval(float y, float gp) {
    float u = fmaf(y, INVPI, gp);
    float cc = __builtin_amdgcn_cosf(u);
    return fmaf(-0.5f, cc, 0.5f - y);
}

// ---------------- K0: prep — weight converts, ODE table, w3a transpose ----------------
// blocks   0..127 : w2 -> bf16 (8 elem/thread)
// blocks 128..143 : w3 yt-part -> bf16
// blocks 144..159 : 4096-entry ODE table
// blocks 160..671 : w3a transpose to [1024][128] f32
__global__ void k_prep(const float* __restrict__ w2W, const float* __restrict__ w3W,
                       const float* __restrict__ wp,
                       unsigned short* __restrict__ w2bf, unsigned short* __restrict__ w3bbf,
                       float* __restrict__ tbl, float* __restrict__ w3aT) {
    int blk = blockIdx.x;
    if (blk < 128) {
        int i = (blk * 256 + threadIdx.x) * 8;
        const float4* s4 = reinterpret_cast<const float4*>(w2W + i);
        float4 a = s4[0], b = s4[1];
        u16x8 o;
        o[0] = f2bf(a.x); o[1] = f2bf(a.y); o[2] = f2bf(a.z); o[3] = f2bf(a.w);
        o[4] = f2bf(b.x); o[5] = f2bf(b.y); o[6] = f2bf(b.z); o[7] = f2bf(b.w);
        *reinterpret_cast<u16x8*>(w2bf + i) = o;
        return;
    }
    if (blk < 144) {
        int idx = ((blk - 128) * 256 + threadIdx.x) * 8;   // < 32768
        int j = idx >> 8, dk = idx & 255;
        const float4* s4 = reinterpret_cast<const float4*>(w3W + j * 1280 + 1024 + dk);
        float4 a = s4[0], b = s4[1];
        u16x8 o;
        o[0] = f2bf(a.x); o[1] = f2bf(a.y); o[2] = f2bf(a.z); o[3] = f2bf(a.w);
        o[4] = f2bf(b.x); o[5] = f2bf(b.y); o[6] = f2bf(b.z); o[7] = f2bf(b.w);
        *reinterpret_cast<u16x8*>(w3bbf + idx) = o;
        return;
    }
    if (blk < 160) {
        int gid = (blk - 144) * 256 + threadIdx.x;   // 0..4095

        float c[21];
#pragma unroll
        for (int g = 0; g < 21; ++g) c[g] = 0.f;
        {
            float wv[10];
#pragma unroll
            for (int t = 0; t < 10; ++t) wv[t] = wp[t];
            float m = wv[0];
#pragma unroll
            for (int t = 1; t < 10; ++t) m = fmaxf(m, wv[t]);
            float s = 0.f;
#pragma unroll
            for (int t = 0; t < 10; ++t) { wv[t] = __expf(wv[t] - m); s += wv[t]; }
            float inv = 1.f / s;
            const int   idxs[10]  = {0, 2, 4, 6, 8, 11, 13, 15, 17, 19};
            const float fracs[10] = {0.f, 0.22222222f, 0.44444445f, 0.6666667f, 0.8888889f,
                                     0.11111111f, 0.33333334f, 0.5555556f, 0.7777778f, 1.0f};
#pragma unroll
            for (int t = 0; t < 10; ++t) {
                float w = wv[t] * inv;
                c[idxs[t]]     += w * (1.f - fracs[t]);
                c[idxs[t] + 1] += w * fracs[t];
            }
        }

        float gamma = gid * TBL_STEP;
        float gp = gamma * INVPI;
        float y = 0.f, acc = 0.f;
#pragma unroll
        for (int st = 0; st < 20; ++st) {
            float k1 = feval(y, gp);
            float k2 = feval(fmaf(0.05f, k1, y), gp);
            float k3 = feval(fmaf(0.05f, k2, y), gp);
            float k4 = feval(fmaf(0.1f,  k3, y), gp);
            float sm = k1 + k4;
            sm = fmaf(2.f, k2, sm);
            sm = fmaf(2.f, k3, sm);
            y  = fmaf(0.1f / 6.0f, sm, y);
            acc = fmaf(c[st + 1], y, acc);
        }
        tbl[gid] = acc;
        return;
    }
    // w3a transpose: w3aT[c*128 + j] = w3W[j*1280 + c], c<1024
    {
        int i = (blk - 160) * 256 + threadIdx.x;   // 0..131071
        int c = i & 1023, j = i >> 10;
        w3aT[c * 128 + j] = w3W[j * 1280 + c];
    }
}

// ---------------- K1: per-batch mega-kernel ----------------
// 256 blocks (1 per batch, 1 per CU) x 512 threads (8 waves).
// P1: feature+yt -> LDS (swizzled bf16), nothing to global.
// P2: x2 = relu(feature @ w2^T + b2); col-max over n -> xs[1024].
// P3: v[j] = xs @ w3a^T[.,j] + b3  (f32) -> vs[128].
// P4: h3 = relu(yt @ w3b^T + vs)  (MFMA) -> hs (rotation-swizzled f32).
// P5: out = h3 @ outW^T + outb    (f32).
__global__ void __launch_bounds__(512) k_batch(
    const float* __restrict__ x, const float* __restrict__ w1W, const float* __restrict__ w1b,
    const float* __restrict__ tbl,
    const unsigned short* __restrict__ w2bf, const float* __restrict__ w2b,
    const float* __restrict__ w3aT, const float* __restrict__ w3b,
    const unsigned short* __restrict__ w3bbf,
    const float* __restrict__ outW, const float* __restrict__ outb,
    float* __restrict__ out) {

    __shared__ __align__(1024) char smemA[57344];   // feature (P1-P2); h3 "hs" (P4-P5)
    __shared__ __align__(1024) char smemY[57344];   // yt bf16 (P1, read P4)
    __shared__ float tl[TBL_N];                     // 16 KB ODE table
    __shared__ float w1s[1024];                     // w1W 768 + w1b 256
    __shared__ float xs[1024];                      // col-max of x2
    __shared__ float ps[4][128];                    // v partials
    __shared__ float vs[128];                       // v + bias
    __shared__ float ps2[4][128][2];                // out partials

    const int b = blockIdx.x;
    const int t = threadIdx.x;

    // ---- stage table + w1 ----
    {
        const float4* g4 = reinterpret_cast<const float4*>(tbl);
        float4* l4 = reinterpret_cast<float4*>(tl);
        l4[t] = g4[t];
        l4[t + 512] = g4[t + 512];
        if (t < 192)
            reinterpret_cast<float4*>(w1s)[t] = reinterpret_cast<const float4*>(w1W)[t];
        else if (t >= 256 && t < 320)
            reinterpret_cast<float4*>(w1s + 768)[t - 256] =
                reinterpret_cast<const float4*>(w1b)[t - 256];
    }
    __syncthreads();

    // ---- P1: feature + yt into LDS (rows 100..111 zeroed), XOR-swizzled ----
    {
        const float* xb = x + (size_t)b * 300;
#pragma unroll
        for (int i = 0; i < 7; ++i) {
            int k = t + i * 512;               // 0..3583 : 112 rows x 32 chunks
            int row = k >> 5, ch = k & 31;
            int byte = row * 512 + ((ch * 16) ^ ((row & 7) << 4));
            if (row < 100) {
                float x0 = xb[row * 3], x1 = xb[row * 3 + 1], x2 = xb[row * 3 + 2];
                int d0 = ch * 8;
                u16x8 fv, yv;
#pragma unroll
                for (int j = 0; j < 8; ++j) {
                    int d = d0 + j;
                    float g = fmaf(x0, w1s[d * 3],
                              fmaf(x1, w1s[d * 3 + 1],
                              fmaf(x2, w1s[d * 3 + 2], w1s[768 + d])));
                    g = fmaxf(g, 0.f);
                    fv[j] = f2bf(g);
                    float tt = g * TBL_SCALE;
                    int ii = (int)tt;
                    ii = (ii > TBL_N - 2) ? (TBL_N - 2) : ii;
                    float fr = tt - (float)ii;
                    float a0 = tl[ii], a1 = tl[ii + 1];
                    yv[j] = f2bf(fmaf(fr, a1 - a0, a0));
                }
                *reinterpret_cast<u16x8*>(smemA + byte) = fv;
                *reinterpret_cast<u16x8*>(smemY + byte) = yv;
            } else {
                *reinterpret_cast<f32x4*>(smemA + byte) = (f32x4){0.f, 0.f, 0.f, 0.f};
                *reinterpret_cast<f32x4*>(smemY + byte) = (f32x4){0.f, 0.f, 0.f, 0.f};
            }
        }
    }
    __syncthreads();

    const int wave = t >> 6, lane = t & 63;
    const int col16 = lane & 15, krow = lane >> 4;
    const int sw = (col16 & 7) << 4;

    // ---- P2: GEMM2 + relu + col-max ----
#pragma unroll 1
    for (int q = 0; q < 2; ++q) {
        int colbase = q * 512 + wave * 64;
        const unsigned short* bp = w2bf + (size_t)(colbase + col16) * 256 + krow * 8;

        f32x4 acc[7][4];
#pragma unroll
        for (int mt = 0; mt < 7; ++mt)
#pragma unroll
            for (int ct = 0; ct < 4; ++ct) acc[mt][ct] = (f32x4){0.f, 0.f, 0.f, 0.f};

        bf16x8 Bcur[4], Bnxt[4];
#pragma unroll
        for (int ct = 0; ct < 4; ++ct)
            Bcur[ct] = *reinterpret_cast<const bf16x8*>(bp + ct * 4096);

#pragma unroll
        for (int k0 = 0; k0 < 8; ++k0) {
            int off = (k0 * 64 + krow * 16) ^ sw;
            bf16x8 Af[7];
#pragma unroll
            for (int mt = 0; mt < 7; ++mt)
                Af[mt] = *reinterpret_cast<const bf16x8*>(smemA + (mt * 16 + col16) * 512 + off);
            if (k0 < 7) {
#pragma unroll
                for (int ct = 0; ct < 4; ++ct)
                    Bnxt[ct] = *reinterpret_cast<const bf16x8*>(bp + ct * 4096 + (k0 + 1) * 32);
            }
#pragma unroll
            for (int mt = 0; mt < 7; ++mt)
#pragma unroll
                for (int ct = 0; ct < 4; ++ct)
                    acc[mt][ct] = MFMA16(Af[mt], Bcur[ct], acc[mt][ct]);
#pragma unroll
            for (int ct = 0; ct < 4; ++ct) Bcur[ct] = Bnxt[ct];
        }

        float bias[4], m[4];
#pragma unroll
        for (int ct = 0; ct < 4; ++ct) {
            bias[ct] = w2b[colbase + ct * 16 + col16];
            m[ct] = 0.f;   // true max >= 0 (relu, 100 valid rows)
        }
#pragma unroll
        for (int mt = 0; mt < 7; ++mt) {
#pragma unroll
            for (int r = 0; r < 4; ++r) {
                bool valid = (mt * 16 + krow * 4 + r) < 100;
#pragma unroll
                for (int ct = 0; ct < 4; ++ct) {
                    float v = fmaxf(acc[mt][ct][r] + bias[ct], 0.f);
                    if (valid) m[ct] = fmaxf(m[ct], v);
                }
            }
        }
#pragma unroll
        for (int ct = 0; ct < 4; ++ct) {
            m[ct] = fmaxf(m[ct], __shfl_xor(m[ct], 16));
            m[ct] = fmaxf(m[ct], __shfl_xor(m[ct], 32));
        }
        if (lane < 16) {
#pragma unroll
            for (int ct = 0; ct < 4; ++ct)
                xs[colbase + ct * 16 + lane] = m[ct];
        }
    }
    __syncthreads();

    // ---- P3: v[j] = sum_c xs[c] * w3aT[c][j] ----
    {
        int j = t & 127, cq = t >> 7;        // 4 c-chunks of 256
        const float* wt = w3aT + (size_t)cq * 256 * 128 + j;
        const float* xc = xs + cq * 256;
        float s0 = 0.f, s1 = 0.f;
#pragma unroll 8
        for (int c = 0; c < 256; c += 2) {
            s0 = fmaf(xc[c],     wt[(size_t)c * 128],       s0);
            s1 = fmaf(xc[c + 1], wt[(size_t)(c + 1) * 128], s1);
        }
        ps[cq][j] = s0 + s1;
    }
    __syncthreads();
    if (t < 128)
        vs[t] = ((ps[0][t] + ps[1][t]) + (ps[2][t] + ps[3][t])) + w3b[t];
    // (no barrier needed yet: P4 GEMM reads only smemY; vs consumed after next barrier)

    // ---- P4: h3 GEMM: yt @ w3b^T ; wave owns 16 cols ----
    f32x4 hacc[7];
#pragma unroll
    for (int mt = 0; mt < 7; ++mt) hacc[mt] = (f32x4){0.f, 0.f, 0.f, 0.f};
    {
        const unsigned short* bp4 = w3bbf + (size_t)(wave * 16 + col16) * 256 + krow * 8;
        bf16x8 B4cur = *reinterpret_cast<const bf16x8*>(bp4);
        bf16x8 B4nxt;
#pragma unroll
        for (int k0 = 0; k0 < 8; ++k0) {
            int off = (k0 * 64 + krow * 16) ^ sw;
            bf16x8 Af[7];
#pragma unroll
            for (int mt = 0; mt < 7; ++mt)
                Af[mt] = *reinterpret_cast<const bf16x8*>(smemY + (mt * 16 + col16) * 512 + off);
            if (k0 < 7) B4nxt = *reinterpret_cast<const bf16x8*>(bp4 + (k0 + 1) * 32);
#pragma unroll
            for (int mt = 0; mt < 7; ++mt)
                hacc[mt] = MFMA16(Af[mt], B4cur, hacc[mt]);
            B4cur = B4nxt;
        }
    }
    __syncthreads();   // vs visible; all P2 reads of smemA complete -> safe to overwrite

    // epilogue: hs[row][(col+row)&127] = relu(hacc + vs[col])  (rotation kills bank pileup)
    {
        float* hs = reinterpret_cast<float*>(smemA);
        int col = wave * 16 + col16;
#pragma unroll
        for (int mt = 0; mt < 7; ++mt) {
#pragma unroll
            for (int r = 0; r < 4; ++r) {
                int row = mt * 16 + krow * 4 + r;
                float h = fmaxf(hacc[mt][r] + vs[col], 0.f);
                hs[row * 128 + ((col + row) & 127)] = h;
            }
        }
    }
    __syncthreads();

    // ---- P5: out = h3 @ outW^T + outb ----
    {
        const float* hs = reinterpret_cast<const float*>(smemA);
        int rr = t & 127, half = t >> 7;    // 4 j-chunks of 32
        float p0 = 0.f, p1 = 0.f;
        if (rr < 112) {
            int j0 = half * 32;
#pragma unroll
            for (int u = 0; u < 32; ++u) {
                int j = j0 + u;
                float h = hs[rr * 128 + ((j + rr) & 127)];
                p0 = fmaf(h, outW[j], p0);
                p1 = fmaf(h, outW[128 + j], p1);
            }
        }
        ps2[half][rr][0] = p0;
        ps2[half][rr][1] = p1;
    }
    __syncthreads();
    if (t < 200) {
        int row = t >> 1, c = t & 1;
        out[((size_t)b * 100 + row) * 2 + c] =
            ((ps2[0][row][c] + ps2[1][row][c]) + (ps2[2][row][c] + ps2[3][row][c])) + outb[c];
    }
}

extern "C" void kernel_launch(void* const* d_in, const int* in_sizes, int n_in,
                              void* d_out, int out_size, void* d_ws, size_t ws_size,
                              hipStream_t stream) {
    const float* x    = (const float*)d_in[0];
    const float* w1W  = (const float*)d_in[1];
    const float* w1b  = (const float*)d_in[2];
    const float* w2W  = (const float*)d_in[3];
    const float* w2b  = (const float*)d_in[4];
    const float* w3W  = (const float*)d_in[5];
    const float* w3b  = (const float*)d_in[6];
    const float* outW = (const float*)d_in[7];
    const float* outb = (const float*)d_in[8];
    const float* wp   = (const float*)d_in[9];
    float* out = (float*)d_out;

    char* ws = (char*)d_ws;
    unsigned short* w2bf_  = (unsigned short*)(ws);             // 524,288 B
    unsigned short* w3bbf_ = (unsigned short*)(ws + 524288);    // 65,536 B
    float* tbl             = (float*)(ws + 589824);             // 16,384 B
    float* w3aT            = (float*)(ws + 606208);             // 524,288 B
    // total ws use: 1,130,496 B

    k_prep<<<672, 256, 0, stream>>>(w2W, w3W, wp, w2bf_, w3bbf_, tbl, w3aT);
    k_batch<<<256, 512, 0, stream>>>(x, w1W, w1b, tbl, w2bf_, w2b, w3aT, w3b,
                                     w3bbf_, outW, outb, out);
}